// Round 8
// baseline (136.707 us; speedup 1.0000x reference)
//
#include <hip/hip_runtime.h>

// ---------------------------------------------------------------------------
// StaNet PAM — round 24: r23's twin-wave key-sharing + barrier-free epilogue
// with CORRECTED grid accounting (r23 failed: st1 covered 128/256 tiles, st2
// 64/256 tiles and overran kbase — bookkeeping, not theory). Waves {0,1} of
// a WG process the SAME key range for two q-tiles; waves {2,3} the next.
// Each wave owns a unique (q-tile, slot): direct reg->PART stores, shfl
// rowsum, zero LDS/barriers in attn. st3: 4 waves share one 18KB K/V block.
//   st0: 1024 WGs = 128 tile-pairs x 8 slot-pairs, 16 slots x 512 keys (m8)
//   st1:  512 WGs = 128 tile-pairs x 4 slot-pairs,  8 slots x 256 keys (m4)
//   st2:  128 WGs = 128 tile-pairs x 1 slot-pair,   2 slots x 256 keys (m4)
//   st3:   64 WGs x 4 tiles (1/wave), 1 slot, full 128-key block     (m2)
// proj identical to r18; normconv slot tables {0,16,24,26}/{16,8,2,1}.
//
// Workspace (float offsets), ~63 MB of the 256 MiB pool:
//   Qb   @ ush 0        : 262144 ush  [st][gp][ch] f16 (Q pre-scaled QMUL)
//   Kb   @ ush 262144   : 262144 ush  [st][gp][ch] f16
//   Vf   @ ush 524288   : 2097152 ush [st][blk][g16][b][lane][j] f16,
//                         fragment-major (r17 layout; HW-validated r18)
//   PART @ fl  1310720  : 27*524288 fl [slot][tile][qrow32][ch64]
//   LPART@ fl  15466496 : 27*8192 fl   [slot][gp]
// slots: 0-15 st0; 16-23 st1; 24-25 st2; 26 st3.
// MFMA 32x32x16: A[m][k] m=lane&31,k=8*(lane>>5)+j; B[k][n] n=lane&31;
// C/D col=lane&31, row=(reg&3)+8*(reg>>2)+4*(lane>>5).
// ---------------------------------------------------------------------------

typedef _Float16 f16x8 __attribute__((ext_vector_type(8)));
typedef float f32x16 __attribute__((ext_vector_type(16)));
typedef short bf16x8 __attribute__((ext_vector_type(8)));

__device__ __forceinline__ unsigned short f2bf(float f){
    union{float f;unsigned int i;}v; v.f=f;
    unsigned int r = v.i + 0x7fffu + ((v.i>>16)&1u);
    return (unsigned short)(r>>16);
}
__device__ __forceinline__ unsigned short f2h(float f){
    union{_Float16 h; unsigned short u;}v; v.h = (_Float16)f; return v.u;
}
__device__ __forceinline__ unsigned pack2h(float a, float b){
    auto pk = __builtin_amdgcn_cvt_pkrtz(a, b);
    unsigned u; __builtin_memcpy(&u, &pk, 4); return u;
}
__device__ __forceinline__ float exp2fast(float x){ return __builtin_amdgcn_exp2f(x); }
// force wave-uniform value into an SGPR (value IS uniform in the wave)
__device__ __forceinline__ int rfl(int x){ return __builtin_amdgcn_readfirstlane(x); }

#define QMUL 0.5100697233f   // 8^-0.5 * log2(e), folded into Q

// ---------------------------------------------------------------------------
// Kernel 1: fused Q/K/V projection (identical to r18).
// ---------------------------------------------------------------------------
__global__ __launch_bounds__(256) void proj_all_kernel(
    const float* __restrict__ x1, const float* __restrict__ x2,
    const float* __restrict__ Wq, const float* __restrict__ bq,
    const float* __restrict__ gq, const float* __restrict__ beq,
    const float* __restrict__ Wk, const float* __restrict__ bk,
    const float* __restrict__ gk, const float* __restrict__ bek,
    const float* __restrict__ Wv, const float* __restrict__ bv,
    unsigned short* __restrict__ Qb, unsigned short* __restrict__ Kb,
    unsigned short* __restrict__ Vf)
{
    __shared__ __align__(16) float xs[64][68];
    __shared__ __align__(16) unsigned vqk[64][8];       // [px][0-3 Q | 4-7 K]
    __shared__ __align__(16) unsigned short vv[64][64]; // [ch][key] (natural)

    const int wg = blockIdx.x, st = wg >> 8, rr = wg & 255;
    const int chunk = rr >> 1, cgrp = rr & 1;
    const int lgP = 13 - 2*st, Pm1 = (1<<lgP) - 1;
    const int hb = 6 - st, wlm = (1<<hb) - 1;
    const int t = threadIdx.x;
    const int gp0 = chunk*64;
    const int blk = gp0 >> lgP, p0 = gp0 & Pm1;
    const int si = blk >> st, sj = blk & ((1<<st)-1);
    const int hwbase = ((si<<hb)<<6) | (sj<<hb);

    for (int idx = t; idx < 4096; idx += 256) {
        int c = idx >> 6, g = idx & 63;
        int p = p0 + g, half = p & 1, pw = p >> 1;
        int hw = hwbase | ((pw>>hb)<<6) | (pw & wlm);
        xs[g][c] = (half ? x2 : x1)[c*4096 + hw];
    }
    __syncthreads();

    const int px = t & 63, wv = t >> 6;
    float xr[64];
    #pragma unroll
    for (int q4 = 0; q4 < 16; ++q4)
        *(float4*)&xr[q4*4] = *(const float4*)&xs[px][q4*4];

#define VRANGE(LO,HI)                                              \
    for (int ch = (LO); ch < (HI); ++ch) {                         \
        const int cu = rfl(st*64 + ch);                            \
        const float* wp = Wv + cu*64;                              \
        float d = bv[cu];                                          \
        _Pragma("unroll")                                          \
        for (int k = 0; k < 64; ++k) d += wp[k]*xr[k];             \
        vv[ch][px] = f2h(d);                                       \
    }
#define KPROJ(CH,DST)                                              \
    {   const int cu = rfl(st*8 + (CH));                           \
        const float* wp = Wk + cu*64;                              \
        float d = 0.f;                                             \
        _Pragma("unroll")                                          \
        for (int k = 0; k < 64; ++k) d += wp[k]*xr[k];             \
        float gm = gk[cu];                                         \
        (DST) = gm*(d + bk[cu]) + bek[cu]; }

    if (cgrp == 0) {
        if (wv == 0) {
            float qv8[8];
            for (int ch = 0; ch < 8; ++ch) {
                const int cu = rfl(st*8 + ch);
                const float* wp = Wq + cu*64;
                float d = 0.f;
                #pragma unroll
                for (int k = 0; k < 64; ++k) d += wp[k]*xr[k];
                float gm = gq[cu];
                qv8[ch] = (gm*(d + bq[cu]) + beq[cu])*QMUL;
            }
            #pragma unroll
            for (int i = 0; i < 4; ++i) vqk[px][i] = pack2h(qv8[2*i], qv8[2*i+1]);
            float k0v, k1v; KPROJ(0, k0v) KPROJ(1, k1v)
            vqk[px][4] = pack2h(k0v, k1v);
        } else if (wv == 1) {
            float ka, kb2;
            KPROJ(2, ka) KPROJ(3, kb2) vqk[px][5] = pack2h(ka, kb2);
            KPROJ(4, ka) KPROJ(5, kb2) vqk[px][6] = pack2h(ka, kb2);
            KPROJ(6, ka) KPROJ(7, kb2) vqk[px][7] = pack2h(ka, kb2);
            VRANGE(0, 4)
        } else if (wv == 2) { VRANGE(4, 14) }
        else               { VRANGE(14, 24) }
    } else {
        if      (wv == 0) { VRANGE(24, 34) }
        else if (wv == 1) { VRANGE(34, 44) }
        else if (wv == 2) { VRANGE(44, 54) }
        else              { VRANGE(54, 64) }
    }
#undef VRANGE
#undef KPROJ
    __syncthreads();

    // Fragment-major V store: ush offset within block slab =
    //   p0*64 + kb*1024 + b*512 + (lhi*32 + (ch&31))*8
    unsigned short* Vst = Vf + st*524288 + (blk << (lgP+6));
    if (cgrp == 0) {
        if (t < 64) {
            *(uint4*)(Qb + st*65536 + (gp0 + t)*8) = *(const uint4*)&vqk[t][0];
        } else if (t < 128) {
            int p2 = t - 64;
            *(uint4*)(Kb + st*65536 + (gp0 + p2)*8) = *(const uint4*)&vqk[p2][4];
        }
        if (t < 192) {                   // V ch 0-23 (b=0, l31=ch)
            int ch = t >> 3, q = t & 7;
            int kb = q >> 1, lhi = q & 1;
            unsigned short tmp[8];
            #pragma unroll
            for (int u = 0; u < 8; ++u) {
                int s = q*8 + u;
                tmp[u] = vv[ch][((s&1)<<5) | (s>>1)];
            }
            *(uint4*)(Vst + p0*64 + kb*1024 + (lhi*32 + ch)*8) = *(const uint4*)tmp;
        }
    } else {
        for (int task = t; task < 320; task += 256) {   // V ch 24-63
            int ch = 24 + (task >> 3), q = task & 7;
            int kb = q >> 1, lhi = q & 1;
            int b = (ch >= 32) ? 1 : 0, l31 = ch & 31;
            unsigned short tmp[8];
            #pragma unroll
            for (int u = 0; u < 8; ++u) {
                int s = q*8 + u;
                tmp[u] = vv[ch][((s&1)<<5) | (s>>1)];
            }
            *(uint4*)(Vst + p0*64 + kb*1024 + b*512 + (lhi*32 + l31)*8) = *(const uint4*)tmp;
        }
    }
}

// ---------------------------------------------------------------------------
// Kernel 2: register-direct MFMA attention. 1728 WGs x 256 thr (4 waves).
// Twin-wave key-sharing; unique (q-tile, slot) per wave; zero LDS/barriers.
// ---------------------------------------------------------------------------
template<int NITER>
__device__ __forceinline__ void attn_core(
    const unsigned short* __restrict__ Kg,
    const unsigned short* __restrict__ Vg,
    int kbase, f16x8 qb, int lane, unsigned msk,
    f32x16& acc0, f32x16& acc1, float* rs)
{
    const int l31 = lane & 31;
    for (int it = 0; it < NITER; ++it) {
        const int k0 = kbase + it*64;
        // Unconditional K loads, upper-half lanes zeroed via AND mask.
        uint4 ku0 = *(const uint4*)(Kg + (k0 + l31)*8);
        uint4 ku1 = *(const uint4*)(Kg + (k0 + 32 + l31)*8);
        ku0.x &= msk; ku0.y &= msk; ku0.z &= msk; ku0.w &= msk;
        ku1.x &= msk; ku1.y &= msk; ku1.z &= msk; ku1.w &= msk;
        f16x8 ka0, ka1;
        __builtin_memcpy(&ka0, &ku0, 16);
        __builtin_memcpy(&ka1, &ku1, 16);

        f32x16 S0, S1;
        #pragma unroll
        for (int r = 0; r < 16; ++r) { S0[r] = 0.f; S1[r] = 0.f; }
        S0 = __builtin_amdgcn_mfma_f32_32x32x16_f16(ka0, qb, S0, 0, 0, 0);
        S1 = __builtin_amdgcn_mfma_f32_32x32x16_f16(ka1, qb, S1, 0, 0, 0);

        // lane = q; reg r = key (r&3)+8*(r>>2)+4*(lane>>5) (+32 for S1).
        unsigned pw[16];
        #pragma unroll
        for (int r = 0; r < 16; ++r) {
            float e0 = exp2fast(S0[r]);
            float e1 = exp2fast(S1[r]);
            rs[r & 3] += e0 + e1;
            pw[r] = pack2h(e0, e1);
        }

        #pragma unroll
        for (int kc = 0; kc < 4; ++kc) {
            f16x8 pb;
            __builtin_memcpy(&pb, &pw[kc*4], 16);
            const unsigned short* vbase = Vg + (k0 + kc*16)*64;
            f16x8 vb0 = *(const f16x8*)(vbase + lane*8);          // ch 0-31
            f16x8 vb1 = *(const f16x8*)(vbase + 512 + lane*8);    // ch 32-63
            acc0 = __builtin_amdgcn_mfma_f32_32x32x16_f16(pb, vb0, acc0, 0, 0, 0);
            acc1 = __builtin_amdgcn_mfma_f32_32x32x16_f16(pb, vb1, acc1, 0, 0, 0);
        }
    }
}

__global__ __launch_bounds__(256, 4) void attn_kernel(
    const unsigned short* __restrict__ Qb, const unsigned short* __restrict__ Kb,
    const unsigned short* __restrict__ Vf,
    float* __restrict__ PART, float* __restrict__ LPART)
{
    const int wg = blockIdx.x;
    const int t = threadIdx.x, lane = t & 63, wv = t >> 6;   // wv 0..3
    const int l31 = lane & 31, lhi = lane >> 5;

    int st, qt, slot, kbase, mode;
    if (wg < 1024) {            // st0: 128 tile-pairs x 8 slot-pairs
        st = 0; int tp = wg >> 3, sp = wg & 7;
        qt = tp*2 + (wv & 1);                   // 0..255
        int ls = sp*2 + (wv >> 1);              // 0..15
        slot = ls; kbase = ls*512; mode = 8;    // 16*512 = 8192 keys
    } else if (wg < 1536) {     // st1: 128 tile-pairs x 4 slot-pairs
        st = 1; int r = wg - 1024; int tp = r >> 2, sp = r & 3;
        qt = tp*2 + (wv & 1);                   // 0..255
        int ls = sp*2 + (wv >> 1);              // 0..7
        slot = 16 + ls; kbase = ls*256; mode = 4;  // 8*256 = 2048 keys
    } else if (wg < 1664) {     // st2: 128 tile-pairs x 1 slot-pair
        st = 2; int r = wg - 1536;
        qt = r*2 + (wv & 1);                    // 0..255
        int ls = (wv >> 1);                     // 0..1
        slot = 24 + ls; kbase = ls*256; mode = 4;  // 2*256 = 512 keys
    } else {                    // st3: 64 WGs x 4 tiles (one per wave)
        st = 3; int r = wg - 1664;
        qt = r*4 + wv; slot = 26; kbase = 0; mode = 2;  // full 128-key block
    }

    const int lgP = 13 - 2*st, P = 1 << lgP;
    const int blk = qt >> (lgP - 5);
    const int q0  = (qt & ((P>>5)-1)) * 32;

    const unsigned short* Qg = Qb + st*65536 + blk*P*8;
    const unsigned short* Kg = Kb + st*65536 + blk*P*8;
    const unsigned short* Vg = Vf + st*524288 + blk*P*64;  // fragment-major

    f16x8 qb = *(const f16x8*)(Qg + (q0 + l31)*8);
    const unsigned msk = (lane < 32) ? 0xFFFFFFFFu : 0u;

    f32x16 acc0, acc1;
    #pragma unroll
    for (int r = 0; r < 16; ++r) { acc0[r] = 0.f; acc1[r] = 0.f; }
    float rs[4] = {0.f, 0.f, 0.f, 0.f};

    if      (mode == 8) attn_core<8>(Kg, Vg, kbase, qb, lane, msk, acc0, acc1, rs);
    else if (mode == 4) attn_core<4>(Kg, Vg, kbase, qb, lane, msk, acc0, acc1, rs);
    else                attn_core<2>(Kg, Vg, kbase, qb, lane, msk, acc0, acc1, rs);

    // ---- barrier-free epilogue: direct reg->global, shfl rowsum ----
    float lsum = rs[0] + rs[1] + rs[2] + rs[3];
    lsum += __shfl_xor(lsum, 32);         // combine lane-halves (same q)

    float* Pw = PART + slot*524288 + qt*2048;
    #pragma unroll
    for (int r = 0; r < 16; ++r) {
        int qrow = (r&3) + 8*(r>>2) + 4*lhi;
        Pw[qrow*64 + l31]      = acc0[r];
        Pw[qrow*64 + 32 + l31] = acc1[r];
    }
    if (lane < 32)
        LPART[slot*8192 + qt*32 + l31] = lsum;
}

// ---------------------------------------------------------------------------
// Kernel 3: normconv via MFMA (r21 body; slot tables 16/8/2/1).
// ---------------------------------------------------------------------------
__global__ __launch_bounds__(256) void normconv_kernel(
    const float* __restrict__ PART, const float* __restrict__ LPART,
    const float* __restrict__ Wo, float* __restrict__ out)
{
    __shared__ __align__(16) unsigned short csb[32][264];
    __shared__ __align__(16) unsigned short wof[16384];
    __shared__ float voutf[64][33];
    __shared__ float linv[4][32];
    __shared__ int gpar[4][32];
    const int t = threadIdx.x;
    const int px0 = blockIdx.x * 32;

    {
        int oc = t >> 2, d0 = (t & 3) * 64;
        for (int b = 0; b < 8; ++b) {
            int d = d0 + b*8;
            float4 w0 = *(const float4*)(Wo + oc*256 + d);
            float4 w1 = *(const float4*)(Wo + oc*256 + d + 4);
            unsigned short tmp[8];
            tmp[0]=f2bf(w0.x); tmp[1]=f2bf(w0.y); tmp[2]=f2bf(w0.z); tmp[3]=f2bf(w0.w);
            tmp[4]=f2bf(w1.x); tmp[5]=f2bf(w1.y); tmp[6]=f2bf(w1.z); tmp[7]=f2bf(w1.w);
            *(uint4*)&wof[(d>>3)*512 + oc*8] = *(const uint4*)tmp;
        }
    }
    if (t < 128) {
        const int s0tab[4] = {0,16,24,26};
        const int sctab[4] = {16,8,2,1};
        int stt = t >> 5, i = t & 31;
        int pix = px0 + i;
        int half = pix >> 12, hw = pix & 4095;
        int h = hw >> 6, w = hw & 63;
        int hb = 6 - stt, wlm = (1<<hb)-1;
        int si = h >> hb, sj = w >> hb, hi = h & wlm, wi = w & wlm;
        int blk = (si << stt) | sj;
        int p = (((hi << hb) | wi) << 1) | half;
        int gp = blk*(8192>>(2*stt)) + p;
        gpar[stt][i] = gp;
        int s0 = s0tab[stt];
        float l = LPART[s0*8192 + gp];
        for (int c = 1; c < sctab[stt]; ++c) l += LPART[(s0+c)*8192 + gp];
        linv[stt][i] = 1.f / l;
    }
    __syncthreads();

    {
        const int s0tab[4] = {0,16,24,26};
        const int sctab[4] = {16,8,2,1};
        int gpx = t >> 3, cvg = (t & 7) * 8;
        for (int stt = 0; stt < 4; ++stt) {
            int gp = gpar[stt][gpx];
            const float* p = PART + s0tab[stt]*524288
                           + (gp>>5)*2048 + (gp&31)*64 + cvg;
            float4 a = *(const float4*)p;
            float4 b = *(const float4*)(p + 4);
            for (int c = 1; c < sctab[stt]; ++c) {
                float4 a2 = *(const float4*)(p + c*524288);
                float4 b2 = *(const float4*)(p + c*524288 + 4);
                a.x+=a2.x; a.y+=a2.y; a.z+=a2.z; a.w+=a2.w;
                b.x+=b2.x; b.y+=b2.y; b.z+=b2.z; b.w+=b2.w;
            }
            float li = linv[stt][gpx];
            unsigned short tmp[8];
            tmp[0]=f2bf(a.x*li); tmp[1]=f2bf(a.y*li); tmp[2]=f2bf(a.z*li); tmp[3]=f2bf(a.w*li);
            tmp[4]=f2bf(b.x*li); tmp[5]=f2bf(b.y*li); tmp[6]=f2bf(b.z*li); tmp[7]=f2bf(b.w*li);
            *(uint4*)&csb[gpx][stt*64 + cvg] = *(const uint4*)tmp;
        }
    }
    __syncthreads();

    const int lane = t & 63, wvv = t >> 6;
    const int l31 = lane & 31, lhi = lane >> 5;
    const int nh = wvv & 1, kh = wvv >> 1;
    f32x16 acc;
    #pragma unroll
    for (int r = 0; r < 16; ++r) acc[r] = 0.f;
    #pragma unroll
    for (int s = 0; s < 8; ++s) {
        int dg = kh*16 + s*2 + lhi;
        bf16x8 a = *(const bf16x8*)&csb[l31][kh*128 + s*16 + 8*lhi];
        bf16x8 b = *(const bf16x8*)&wof[dg*512 + (nh*32 + l31)*8];
        acc = __builtin_amdgcn_mfma_f32_32x32x16_bf16(a, b, acc, 0, 0, 0);
    }
    if (kh == 0) {
        #pragma unroll
        for (int r = 0; r < 16; ++r)
            voutf[nh*32 + l31][(r&3) + 8*(r>>2) + 4*lhi] = acc[r];
    }
    __syncthreads();
    if (kh == 1) {
        #pragma unroll
        for (int r = 0; r < 16; ++r)
            voutf[nh*32 + l31][(r&3) + 8*(r>>2) + 4*lhi] += acc[r];
    }
    __syncthreads();

    const int half = px0 >> 12, hw0 = px0 & 4095;
    float* obase = out + half*262144 + hw0;
    #pragma unroll
    for (int r = 0; r < 8; ++r) {
        int idx = t + r*256;
        int oc = idx >> 5, pxi = idx & 31;
        obase[oc*4096 + pxi] = voutf[oc][pxi];
    }
}

// ---------------------------------------------------------------------------
extern "C" void kernel_launch(void* const* d_in, const int* in_sizes, int n_in,
                              void* d_out, int out_size, void* d_ws, size_t ws_size,
                              hipStream_t stream)
{
    (void)out_size; (void)ws_size;
    const float *x1, *x2, *Wq, *bq, *gq, *beq, *Wk, *bk, *gk, *bek, *Wv, *bv, *Wo;

    if (n_in >= 13 && in_sizes[0] == 2048) {       // sorted-key order (insurance)
        Wk  = (const float*)d_in[0];  Wo  = (const float*)d_in[1];
        Wq  = (const float*)d_in[2];  Wv  = (const float*)d_in[3];
        bek = (const float*)d_in[4];  beq = (const float*)d_in[5];
        bk  = (const float*)d_in[6];  bq  = (const float*)d_in[7];
        bv  = (const float*)d_in[8];  gk  = (const float*)d_in[9];
        gq  = (const float*)d_in[10];
        x1  = (const float*)d_in[11]; x2  = (const float*)d_in[12];
    } else {                                        // insertion order (proven)
        x1  = (const float*)d_in[0];  x2  = (const float*)d_in[1];
        Wq  = (const float*)d_in[2];  bq  = (const float*)d_in[3];
        gq  = (const float*)d_in[4];  beq = (const float*)d_in[5];
        Wk  = (const float*)d_in[6];  bk  = (const float*)d_in[7];
        gk  = (const float*)d_in[8];  bek = (const float*)d_in[9];
        Wv  = (const float*)d_in[10]; bv  = (const float*)d_in[11];
        Wo  = (const float*)d_in[12];
    }

    unsigned short* Qb = (unsigned short*)d_ws;     // 262144 ush
    unsigned short* Kb = Qb + 262144;               // 262144 ush
    unsigned short* Vf = Kb + 262144;               // 2097152 ush
    float* PART  = (float*)d_ws + 1310720;          // 27*524288 fl
    float* LPART = PART + 14155776;                 // 27*8192 fl

    proj_all_kernel<<<1024, 256, 0, stream>>>(x1,x2,Wq,bq,gq,beq,Wk,bk,gk,bek,Wv,bv,Qb,Kb,Vf);
    attn_kernel<<<1728, 256, 0, stream>>>(Qb,Kb,Vf,PART,LPART);
    normconv_kernel<<<256, 256, 0, stream>>>(PART, LPART, Wo, (float*)d_out);
}

// Round 9
// 132.088 us; speedup vs baseline: 1.0350x; 1.0350x over previous
//
#include <hip/hip_runtime.h>

// ---------------------------------------------------------------------------
// StaNet PAM — round 25: r22 base + explicit load prefetch in attn k-loop.
// Theory: r17->r18's -15us came from shortening the per-iter serial chain;
// six redistribution variants since were null. The last untouched chain term
// is load-to-use distance: at 80-96 VGPR the compiler schedules K/V loads
// just-in-time -> ~2x250cy L2 latency per iteration, unhidden at 2-6
// waves/SIMD. This round: ALL 10 loads (2 K + 8 V, named regs) issue at the
// TOP of each iteration, pinned by sched_barrier(0); QK MFMA waits only on
// K; V arrives under the MFMA+exp+pack phase. VGPR ~170 (launch_bounds
// (256,2) — r22's (256,4) would spill), occupancy deliberately ~2 waves/SIMD:
// trading occupancy for chain length, the inverse of the nulls.
// proj identical to r18; normconv identical to r22 (12-slot tables).
//
// Workspace (float offsets), ~30.8 MB of the 256 MiB pool:
//   Qb   @ ush 0       : 262144 ush  [st][gp][ch] f16 (Q pre-scaled QMUL)
//   Kb   @ ush 262144  : 262144 ush  [st][gp][ch] f16
//   Vf   @ ush 524288  : 2097152 ush [st][blk][g16][b][lane][j] f16,
//                        fragment-major (r17 layout; HW-validated r18)
//   PART @ fl  1310720 : 12*524288 fl [slot][tile][qrow32][ch64]
//   LPART@ fl  7602176 : 12*8192 fl   [slot][gp]
// slots: 0-7 = st0 eighths; 8,9 = st1 halves; 10 = st2; 11 = st3.
// MFMA 32x32x16: A[m][k] m=lane&31,k=8*(lane>>5)+j; B[k][n] n=lane&31;
// C/D col=lane&31, row=(reg&3)+8*(reg>>2)+4*(lane>>5).
// ---------------------------------------------------------------------------

typedef _Float16 f16x8 __attribute__((ext_vector_type(8)));
typedef float f32x16 __attribute__((ext_vector_type(16)));
typedef short bf16x8 __attribute__((ext_vector_type(8)));

__device__ __forceinline__ unsigned short f2bf(float f){
    union{float f;unsigned int i;}v; v.f=f;
    unsigned int r = v.i + 0x7fffu + ((v.i>>16)&1u);
    return (unsigned short)(r>>16);
}
__device__ __forceinline__ unsigned short f2h(float f){
    union{_Float16 h; unsigned short u;}v; v.h = (_Float16)f; return v.u;
}
__device__ __forceinline__ unsigned pack2h(float a, float b){
    auto pk = __builtin_amdgcn_cvt_pkrtz(a, b);
    unsigned u; __builtin_memcpy(&u, &pk, 4); return u;
}
__device__ __forceinline__ float exp2fast(float x){ return __builtin_amdgcn_exp2f(x); }
// force wave-uniform value into an SGPR (value IS uniform in the wave)
__device__ __forceinline__ int rfl(int x){ return __builtin_amdgcn_readfirstlane(x); }

#define QMUL 0.5100697233f   // 8^-0.5 * log2(e), folded into Q

// ---------------------------------------------------------------------------
// Kernel 1: fused Q/K/V projection (identical to r18).
// ---------------------------------------------------------------------------
__global__ __launch_bounds__(256) void proj_all_kernel(
    const float* __restrict__ x1, const float* __restrict__ x2,
    const float* __restrict__ Wq, const float* __restrict__ bq,
    const float* __restrict__ gq, const float* __restrict__ beq,
    const float* __restrict__ Wk, const float* __restrict__ bk,
    const float* __restrict__ gk, const float* __restrict__ bek,
    const float* __restrict__ Wv, const float* __restrict__ bv,
    unsigned short* __restrict__ Qb, unsigned short* __restrict__ Kb,
    unsigned short* __restrict__ Vf)
{
    __shared__ __align__(16) float xs[64][68];
    __shared__ __align__(16) unsigned vqk[64][8];       // [px][0-3 Q | 4-7 K]
    __shared__ __align__(16) unsigned short vv[64][64]; // [ch][key] (natural)

    const int wg = blockIdx.x, st = wg >> 8, rr = wg & 255;
    const int chunk = rr >> 1, cgrp = rr & 1;
    const int lgP = 13 - 2*st, Pm1 = (1<<lgP) - 1;
    const int hb = 6 - st, wlm = (1<<hb) - 1;
    const int t = threadIdx.x;
    const int gp0 = chunk*64;
    const int blk = gp0 >> lgP, p0 = gp0 & Pm1;
    const int si = blk >> st, sj = blk & ((1<<st)-1);
    const int hwbase = ((si<<hb)<<6) | (sj<<hb);

    for (int idx = t; idx < 4096; idx += 256) {
        int c = idx >> 6, g = idx & 63;
        int p = p0 + g, half = p & 1, pw = p >> 1;
        int hw = hwbase | ((pw>>hb)<<6) | (pw & wlm);
        xs[g][c] = (half ? x2 : x1)[c*4096 + hw];
    }
    __syncthreads();

    const int px = t & 63, wv = t >> 6;
    float xr[64];
    #pragma unroll
    for (int q4 = 0; q4 < 16; ++q4)
        *(float4*)&xr[q4*4] = *(const float4*)&xs[px][q4*4];

#define VRANGE(LO,HI)                                              \
    for (int ch = (LO); ch < (HI); ++ch) {                         \
        const int cu = rfl(st*64 + ch);                            \
        const float* wp = Wv + cu*64;                              \
        float d = bv[cu];                                          \
        _Pragma("unroll")                                          \
        for (int k = 0; k < 64; ++k) d += wp[k]*xr[k];             \
        vv[ch][px] = f2h(d);                                       \
    }
#define KPROJ(CH,DST)                                              \
    {   const int cu = rfl(st*8 + (CH));                           \
        const float* wp = Wk + cu*64;                              \
        float d = 0.f;                                             \
        _Pragma("unroll")                                          \
        for (int k = 0; k < 64; ++k) d += wp[k]*xr[k];             \
        float gm = gk[cu];                                         \
        (DST) = gm*(d + bk[cu]) + bek[cu]; }

    if (cgrp == 0) {
        if (wv == 0) {
            float qv8[8];
            for (int ch = 0; ch < 8; ++ch) {
                const int cu = rfl(st*8 + ch);
                const float* wp = Wq + cu*64;
                float d = 0.f;
                #pragma unroll
                for (int k = 0; k < 64; ++k) d += wp[k]*xr[k];
                float gm = gq[cu];
                qv8[ch] = (gm*(d + bq[cu]) + beq[cu])*QMUL;
            }
            #pragma unroll
            for (int i = 0; i < 4; ++i) vqk[px][i] = pack2h(qv8[2*i], qv8[2*i+1]);
            float k0v, k1v; KPROJ(0, k0v) KPROJ(1, k1v)
            vqk[px][4] = pack2h(k0v, k1v);
        } else if (wv == 1) {
            float ka, kb2;
            KPROJ(2, ka) KPROJ(3, kb2) vqk[px][5] = pack2h(ka, kb2);
            KPROJ(4, ka) KPROJ(5, kb2) vqk[px][6] = pack2h(ka, kb2);
            KPROJ(6, ka) KPROJ(7, kb2) vqk[px][7] = pack2h(ka, kb2);
            VRANGE(0, 4)
        } else if (wv == 2) { VRANGE(4, 14) }
        else               { VRANGE(14, 24) }
    } else {
        if      (wv == 0) { VRANGE(24, 34) }
        else if (wv == 1) { VRANGE(34, 44) }
        else if (wv == 2) { VRANGE(44, 54) }
        else              { VRANGE(54, 64) }
    }
#undef VRANGE
#undef KPROJ
    __syncthreads();

    // Fragment-major V store: ush offset within block slab =
    //   p0*64 + kb*1024 + b*512 + (lhi*32 + (ch&31))*8
    unsigned short* Vst = Vf + st*524288 + (blk << (lgP+6));
    if (cgrp == 0) {
        if (t < 64) {
            *(uint4*)(Qb + st*65536 + (gp0 + t)*8) = *(const uint4*)&vqk[t][0];
        } else if (t < 128) {
            int p2 = t - 64;
            *(uint4*)(Kb + st*65536 + (gp0 + p2)*8) = *(const uint4*)&vqk[p2][4];
        }
        if (t < 192) {                   // V ch 0-23 (b=0, l31=ch)
            int ch = t >> 3, q = t & 7;
            int kb = q >> 1, lhi = q & 1;
            unsigned short tmp[8];
            #pragma unroll
            for (int u = 0; u < 8; ++u) {
                int s = q*8 + u;
                tmp[u] = vv[ch][((s&1)<<5) | (s>>1)];
            }
            *(uint4*)(Vst + p0*64 + kb*1024 + (lhi*32 + ch)*8) = *(const uint4*)tmp;
        }
    } else {
        for (int task = t; task < 320; task += 256) {   // V ch 24-63
            int ch = 24 + (task >> 3), q = task & 7;
            int kb = q >> 1, lhi = q & 1;
            int b = (ch >= 32) ? 1 : 0, l31 = ch & 31;
            unsigned short tmp[8];
            #pragma unroll
            for (int u = 0; u < 8; ++u) {
                int s = q*8 + u;
                tmp[u] = vv[ch][((s&1)<<5) | (s>>1)];
            }
            *(uint4*)(Vst + p0*64 + kb*1024 + b*512 + (lhi*32 + l31)*8) = *(const uint4*)tmp;
        }
    }
}

// ---------------------------------------------------------------------------
// Kernel 2: register-direct MFMA attention with explicit load prefetch.
// 3072 WGs x 256 thr (4 waves). All 10 loads issue at iteration top
// (sched_barrier-pinned); QK waits only on K; V lands under MFMA+exp.
// ---------------------------------------------------------------------------
template<int NITER>
__device__ __forceinline__ void attn_core(
    const unsigned short* __restrict__ Kg,
    const unsigned short* __restrict__ Vg,
    int kbase, f16x8 qb, int lane, unsigned msk,
    f32x16& acc0, f32x16& acc1, float* rs)
{
    const int l31 = lane & 31;
    for (int it = 0; it < NITER; ++it) {
        const int k0 = kbase + it*64;
        // ---- issue ALL loads for this iteration first (2 K + 8 V) ----
        uint4 ku0 = *(const uint4*)(Kg + (k0 + l31)*8);
        uint4 ku1 = *(const uint4*)(Kg + (k0 + 32 + l31)*8);
        const unsigned short* vb = Vg + k0*64 + lane*8;
        f16x8 v00 = *(const f16x8*)(vb);                // kc0, ch 0-31
        f16x8 v01 = *(const f16x8*)(vb + 512);          // kc0, ch 32-63
        f16x8 v10 = *(const f16x8*)(vb + 1024);         // kc1
        f16x8 v11 = *(const f16x8*)(vb + 1536);
        f16x8 v20 = *(const f16x8*)(vb + 2048);         // kc2
        f16x8 v21 = *(const f16x8*)(vb + 2560);
        f16x8 v30 = *(const f16x8*)(vb + 3072);         // kc3
        f16x8 v31 = *(const f16x8*)(vb + 3584);
        __builtin_amdgcn_sched_barrier(0);   // pin: loads stay above

        ku0.x &= msk; ku0.y &= msk; ku0.z &= msk; ku0.w &= msk;
        ku1.x &= msk; ku1.y &= msk; ku1.z &= msk; ku1.w &= msk;
        f16x8 ka0, ka1;
        __builtin_memcpy(&ka0, &ku0, 16);
        __builtin_memcpy(&ka1, &ku1, 16);

        f32x16 S0, S1;
        #pragma unroll
        for (int r = 0; r < 16; ++r) { S0[r] = 0.f; S1[r] = 0.f; }
        S0 = __builtin_amdgcn_mfma_f32_32x32x16_f16(ka0, qb, S0, 0, 0, 0);
        S1 = __builtin_amdgcn_mfma_f32_32x32x16_f16(ka1, qb, S1, 0, 0, 0);

        // lane = q; reg r = key (r&3)+8*(r>>2)+4*(lane>>5) (+32 for S1).
        unsigned pw[16];
        #pragma unroll
        for (int r = 0; r < 16; ++r) {
            float e0 = exp2fast(S0[r]);
            float e1 = exp2fast(S1[r]);
            rs[r & 3] += e0 + e1;
            pw[r] = pack2h(e0, e1);
        }

        f16x8 pb0, pb1, pb2, pb3;
        __builtin_memcpy(&pb0, &pw[0],  16);
        __builtin_memcpy(&pb1, &pw[4],  16);
        __builtin_memcpy(&pb2, &pw[8],  16);
        __builtin_memcpy(&pb3, &pw[12], 16);
        acc0 = __builtin_amdgcn_mfma_f32_32x32x16_f16(pb0, v00, acc0, 0, 0, 0);
        acc1 = __builtin_amdgcn_mfma_f32_32x32x16_f16(pb0, v01, acc1, 0, 0, 0);
        acc0 = __builtin_amdgcn_mfma_f32_32x32x16_f16(pb1, v10, acc0, 0, 0, 0);
        acc1 = __builtin_amdgcn_mfma_f32_32x32x16_f16(pb1, v11, acc1, 0, 0, 0);
        acc0 = __builtin_amdgcn_mfma_f32_32x32x16_f16(pb2, v20, acc0, 0, 0, 0);
        acc1 = __builtin_amdgcn_mfma_f32_32x32x16_f16(pb2, v21, acc1, 0, 0, 0);
        acc0 = __builtin_amdgcn_mfma_f32_32x32x16_f16(pb3, v30, acc0, 0, 0, 0);
        acc1 = __builtin_amdgcn_mfma_f32_32x32x16_f16(pb3, v31, acc1, 0, 0, 0);
    }
}

__global__ __launch_bounds__(256, 2) void attn_kernel(
    const unsigned short* __restrict__ Qb, const unsigned short* __restrict__ Kb,
    const unsigned short* __restrict__ Vf,
    float* __restrict__ PART, float* __restrict__ LPART)
{
    __shared__ __align__(16) float BB[8192];    // 4 x 2048 partial buffers
    __shared__ float SCm[4][64];

    const int wg = blockIdx.x;
    const int t = threadIdx.x, lane = t & 63, wv = t >> 6;   // wv 0..3
    const int l31 = lane & 31, lhi = lane >> 5;

    int st, qt, slot, kbase, mode;
    if (wg < 2048)      { st=0; qt=wg>>3; slot=wg&7;
                          kbase=(wg&7)*1024 + wv*256; mode=4; }
    else if (wg < 2560) { int r=wg-2048; st=1; qt=r>>1; slot=8+(r&1);
                          kbase=(r&1)*1024 + wv*256;  mode=4; }
    else if (wg < 2816) { st=2; qt=wg-2560; slot=10; kbase=wv*128; mode=2; }
    else                { st=3; qt=wg-2816; slot=11; kbase=wv*64;
                          mode=(wv<2)?1:0; }

    const int lgP = 13 - 2*st, P = 1 << lgP;
    const int blk = qt >> (lgP - 5);
    const int q0  = (qt & ((P>>5)-1)) * 32;

    const unsigned short* Qg = Qb + st*65536 + blk*P*8;
    const unsigned short* Kg = Kb + st*65536 + blk*P*8;
    const unsigned short* Vg = Vf + st*524288 + blk*P*64;  // fragment-major

    f16x8 qb = *(const f16x8*)(Qg + (q0 + l31)*8);
    const unsigned msk = (lane < 32) ? 0xFFFFFFFFu : 0u;

    f32x16 acc0, acc1;
    #pragma unroll
    for (int r = 0; r < 16; ++r) { acc0[r] = 0.f; acc1[r] = 0.f; }
    float rs[4] = {0.f, 0.f, 0.f, 0.f};

    if      (mode == 4) attn_core<4>(Kg, Vg, kbase, qb, lane, msk, acc0, acc1, rs);
    else if (mode == 2) attn_core<2>(Kg, Vg, kbase, qb, lane, msk, acc0, acc1, rs);
    else if (mode == 1) attn_core<1>(Kg, Vg, kbase, qb, lane, msk, acc0, acc1, rs);

    // ---- lean 1-barrier epilogue (r22) ----
    SCm[wv][lane] = rs[0] + rs[1] + rs[2] + rs[3];
    {
        float* B = BB + wv*2048;
        #pragma unroll
        for (int r = 0; r < 16; ++r) {
            int qrow = (r&3) + 8*(r>>2) + 4*lhi;
            B[qrow*64 + l31]      = acc0[r];
            B[qrow*64 + 32 + l31] = acc1[r];
        }
    }
    __syncthreads();

    float4* Pslab4 = (float4*)(PART + slot*524288 + qt*2048);
    const float4* B4 = (const float4*)BB;
    #pragma unroll
    for (int r = 0; r < 2; ++r) {
        int idx = t + r*256;
        float4 a = B4[idx], b = B4[idx+512], c = B4[idx+1024], d = B4[idx+1536];
        Pslab4[idx] = float4{a.x+b.x+c.x+d.x, a.y+b.y+c.y+d.y,
                             a.z+b.z+c.z+d.z, a.w+b.w+c.w+d.w};
    }
    if (t < 32)
        LPART[slot*8192 + qt*32 + t] =
            (SCm[0][t] + SCm[0][32+t]) + (SCm[1][t] + SCm[1][32+t])
          + (SCm[2][t] + SCm[2][32+t]) + (SCm[3][t] + SCm[3][32+t]);
}

// ---------------------------------------------------------------------------
// Kernel 3: normconv via MFMA (r22 body; st0 sums 8 partial slots).
// ---------------------------------------------------------------------------
__global__ __launch_bounds__(256) void normconv_kernel(
    const float* __restrict__ PART, const float* __restrict__ LPART,
    const float* __restrict__ Wo, float* __restrict__ out)
{
    __shared__ __align__(16) unsigned short csb[32][264];
    __shared__ __align__(16) unsigned short wof[16384];
    __shared__ float voutf[64][33];
    __shared__ float linv[4][32];
    __shared__ int gpar[4][32];
    const int t = threadIdx.x;
    const int px0 = blockIdx.x * 32;

    {
        int oc = t >> 2, d0 = (t & 3) * 64;
        for (int b = 0; b < 8; ++b) {
            int d = d0 + b*8;
            float4 w0 = *(const float4*)(Wo + oc*256 + d);
            float4 w1 = *(const float4*)(Wo + oc*256 + d + 4);
            unsigned short tmp[8];
            tmp[0]=f2bf(w0.x); tmp[1]=f2bf(w0.y); tmp[2]=f2bf(w0.z); tmp[3]=f2bf(w0.w);
            tmp[4]=f2bf(w1.x); tmp[5]=f2bf(w1.y); tmp[6]=f2bf(w1.z); tmp[7]=f2bf(w1.w);
            *(uint4*)&wof[(d>>3)*512 + oc*8] = *(const uint4*)tmp;
        }
    }
    if (t < 128) {
        const int s0tab[4] = {0,8,10,11};
        const int sctab[4] = {8,2,1,1};
        int stt = t >> 5, i = t & 31;
        int pix = px0 + i;
        int half = pix >> 12, hw = pix & 4095;
        int h = hw >> 6, w = hw & 63;
        int hb = 6 - stt, wlm = (1<<hb)-1;
        int si = h >> hb, sj = w >> hb, hi = h & wlm, wi = w & wlm;
        int blk = (si << stt) | sj;
        int p = (((hi << hb) | wi) << 1) | half;
        int gp = blk*(8192>>(2*stt)) + p;
        gpar[stt][i] = gp;
        int s0 = s0tab[stt];
        float l = LPART[s0*8192 + gp];
        for (int c = 1; c < sctab[stt]; ++c) l += LPART[(s0+c)*8192 + gp];
        linv[stt][i] = 1.f / l;
    }
    __syncthreads();

    {
        const int s0tab[4] = {0,8,10,11};
        const int sctab[4] = {8,2,1,1};
        int gpx = t >> 3, cvg = (t & 7) * 8;
        for (int stt = 0; stt < 4; ++stt) {
            int gp = gpar[stt][gpx];
            const float* p = PART + s0tab[stt]*524288
                           + (gp>>5)*2048 + (gp&31)*64 + cvg;
            float4 a = *(const float4*)p;
            float4 b = *(const float4*)(p + 4);
            for (int c = 1; c < sctab[stt]; ++c) {
                float4 a2 = *(const float4*)(p + c*524288);
                float4 b2 = *(const float4*)(p + c*524288 + 4);
                a.x+=a2.x; a.y+=a2.y; a.z+=a2.z; a.w+=a2.w;
                b.x+=b2.x; b.y+=b2.y; b.z+=b2.z; b.w+=b2.w;
            }
            float li = linv[stt][gpx];
            unsigned short tmp[8];
            tmp[0]=f2bf(a.x*li); tmp[1]=f2bf(a.y*li); tmp[2]=f2bf(a.z*li); tmp[3]=f2bf(a.w*li);
            tmp[4]=f2bf(b.x*li); tmp[5]=f2bf(b.y*li); tmp[6]=f2bf(b.z*li); tmp[7]=f2bf(b.w*li);
            *(uint4*)&csb[gpx][stt*64 + cvg] = *(const uint4*)tmp;
        }
    }
    __syncthreads();

    const int lane = t & 63, wvv = t >> 6;
    const int l31 = lane & 31, lhi = lane >> 5;
    const int nh = wvv & 1, kh = wvv >> 1;
    f32x16 acc;
    #pragma unroll
    for (int r = 0; r < 16; ++r) acc[r] = 0.f;
    #pragma unroll
    for (int s = 0; s < 8; ++s) {
        int dg = kh*16 + s*2 + lhi;
        bf16x8 a = *(const bf16x8*)&csb[l31][kh*128 + s*16 + 8*lhi];
        bf16x8 b = *(const bf16x8*)&wof[dg*512 + (nh*32 + l31)*8];
        acc = __builtin_amdgcn_mfma_f32_32x32x16_bf16(a, b, acc, 0, 0, 0);
    }
    if (kh == 0) {
        #pragma unroll
        for (int r = 0; r < 16; ++r)
            voutf[nh*32 + l31][(r&3) + 8*(r>>2) + 4*lhi] = acc[r];
    }
    __syncthreads();
    if (kh == 1) {
        #pragma unroll
        for (int r = 0; r < 16; ++r)
            voutf[nh*32 + l31][(r&3) + 8*(r>>2) + 4*lhi] += acc[r];
    }
    __syncthreads();

    const int half = px0 >> 12, hw0 = px0 & 4095;
    float* obase = out + half*262144 + hw0;
    #pragma unroll
    for (int r = 0; r < 8; ++r) {
        int idx = t + r*256;
        int oc = idx >> 5, pxi = idx & 31;
        obase[oc*4096 + pxi] = voutf[oc][pxi];
    }
}

// ---------------------------------------------------------------------------
extern "C" void kernel_launch(void* const* d_in, const int* in_sizes, int n_in,
                              void* d_out, int out_size, void* d_ws, size_t ws_size,
                              hipStream_t stream)
{
    (void)out_size; (void)ws_size;
    const float *x1, *x2, *Wq, *bq, *gq, *beq, *Wk, *bk, *gk, *bek, *Wv, *bv, *Wo;

    if (n_in >= 13 && in_sizes[0] == 2048) {       // sorted-key order (insurance)
        Wk  = (const float*)d_in[0];  Wo  = (const float*)d_in[1];
        Wq  = (const float*)d_in[2];  Wv  = (const float*)d_in[3];
        bek = (const float*)d_in[4];  beq = (const float*)d_in[5];
        bk  = (const float*)d_in[6];  bq  = (const float*)d_in[7];
        bv  = (const float*)d_in[8];  gk  = (const float*)d_in[9];
        gq  = (const float*)d_in[10];
        x1  = (const float*)d_in[11]; x2  = (const float*)d_in[12];
    } else {                                        // insertion order (proven)
        x1  = (const float*)d_in[0];  x2  = (const float*)d_in[1];
        Wq  = (const float*)d_in[2];  bq  = (const float*)d_in[3];
        gq  = (const float*)d_in[4];  beq = (const float*)d_in[5];
        Wk  = (const float*)d_in[6];  bk  = (const float*)d_in[7];
        gk  = (const float*)d_in[8];  bek = (const float*)d_in[9];
        Wv  = (const float*)d_in[10]; bv  = (const float*)d_in[11];
        Wo  = (const float*)d_in[12];
    }

    unsigned short* Qb = (unsigned short*)d_ws;     // 262144 ush
    unsigned short* Kb = Qb + 262144;               // 262144 ush
    unsigned short* Vf = Kb + 262144;               // 2097152 ush
    float* PART  = (float*)d_ws + 1310720;          // 12*524288 fl
    float* LPART = PART + 6291456;                  // 98304 fl

    proj_all_kernel<<<1024, 256, 0, stream>>>(x1,x2,Wq,bq,gq,beq,Wk,bk,gk,bek,Wv,bv,Qb,Kb,Vf);
    attn_kernel<<<3072, 256, 0, stream>>>(Qb,Kb,Vf,PART,LPART);
    normconv_kernel<<<256, 256, 0, stream>>>(PART, LPART, Wo, (float*)d_out);
}